// Round 4
// baseline (20.238 us; speedup 1.0000x reference)
//
#include <hip/hip_runtime.h>

// ---------------------------------------------------------------------------
// Quantum conv2d, packed-fp32 + bulk-register-prefetch edition.
// State: f2[16] (re,im) per thread -> complex MAC = 2x v_pk_fma_f32.
// Per channel, ALL 8 gate matrices are prefetched into registers (32x
// ds_read_b128 issued back-to-back) before the Mottonen cascade, so LDS
// latency is paid once per channel and overlaps cascade VALU work.
// ---------------------------------------------------------------------------

typedef float f2 __attribute__((ext_vector_type(2)));

__device__ __forceinline__ f2 pkfma(f2 a, f2 b, f2 c) {
    return __builtin_elementwise_fma(a, b, c);
}
__device__ __forceinline__ f2 swap2(f2 v) {
    return __builtin_shufflevector(v, v, 1, 0);
}

struct GateM { f2 m00rr, m00ni, m01rr, m01ni, m10rr, m10ni, m11rr, m11ni; };

__device__ __forceinline__ GateM load_gate(const float* gp) {
    const float4* p = (const float4*)gp;
    const float4 e0 = p[0], e1 = p[1], e2 = p[2], e3 = p[3];
    GateM G;
    G.m00rr = f2{e0.x, e0.y}; G.m00ni = f2{e0.z, e0.w};
    G.m01rr = f2{e1.x, e1.y}; G.m01ni = f2{e1.z, e1.w};
    G.m10rr = f2{e2.x, e2.y}; G.m10ni = f2{e2.z, e2.w};
    G.m11rr = f2{e3.x, e3.y}; G.m11ni = f2{e3.z, e3.w};
    return G;
}

template<int STRIDE>
__device__ __forceinline__ void apply_gate(f2* s, const GateM G) {
    #pragma unroll
    for (int m0 = 0; m0 < 16; ++m0) {
        if (m0 & STRIDE) continue;
        const int m1 = m0 | STRIDE;
        const f2 a = s[m0], b = s[m1];
        const f2 as = swap2(a), bs = swap2(b);
        f2 o0 = G.m00rr * a;
        o0 = pkfma(G.m00ni, as, o0);
        o0 = pkfma(G.m01rr, b,  o0);
        o0 = pkfma(G.m01ni, bs, o0);
        f2 o1 = G.m10rr * a;
        o1 = pkfma(G.m10ni, as, o1);
        o1 = pkfma(G.m11rr, b,  o1);
        o1 = pkfma(G.m11ni, bs, o1);
        s[m0] = o0; s[m1] = o1;
    }
}

template<int BC, int BT>
__device__ __forceinline__ void apply_cnot(f2* s) {
    #pragma unroll
    for (int m = 0; m < 16; ++m) {
        if ((m & BC) && !(m & BT)) {
            const int m2 = m | BT;
            const f2 t = s[m]; s[m] = s[m2]; s[m2] = t;
        }
    }
}

struct Node { f2 cc, ss, ns; };

// Multiplexed-RY node from un-normalized child sums (scale cancels).
__device__ __forceinline__ Node node_cs(float lo, float hi) {
    const float den = lo + hi;
    const bool ok = den > 1e-30f;
    const float rs = __builtin_amdgcn_rsqf(fmaxf(den, 1e-37f));
    const float c = ok ? __builtin_amdgcn_sqrtf(lo) * rs : 1.0f;
    const float s = ok ? __builtin_amdgcn_sqrtf(hi) * rs : 0.0f;
    return Node{f2{c, c}, f2{s, s}, f2{-s, -s}};
}

template<int I0, int I1>
__device__ __forceinline__ void rot_pair(f2* s, const Node& n) {
    const f2 a = s[I0], b = s[I1];
    s[I0] = pkfma(n.cc, a, n.ns * b);
    s[I1] = pkfma(n.ss, a, n.cc * b);
}

__device__ __forceinline__ void cascade(f2* s, const float* Q) {
    const float s01 = Q[0]+Q[1], s23 = Q[2]+Q[3];
    const float s45 = Q[4]+Q[5], s67 = Q[6]+Q[7];
    const float s03 = s01+s23, s47 = s45+s67, s07 = s03+s47;
    const Node n0  = node_cs(s07,  Q[8]);   // t=0
    const Node n1  = node_cs(s03,  s47);    // t=1 b=0 (b=1 identity)
    const Node n2a = node_cs(s01,  s23);    // t=2 b=0
    const Node n2b = node_cs(s45,  s67);    // t=2 b=1 (b=2,3 identity)
    const Node n3a = node_cs(Q[0], Q[1]);   // t=3 b=0
    const Node n3b = node_cs(Q[2], Q[3]);   // t=3 b=1
    const Node n3c = node_cs(Q[4], Q[5]);   // t=3 b=2
    const Node n3d = node_cs(Q[6], Q[7]);   // t=3 b=3 (b=4..7 identity)

    rot_pair<0, 8>(s, n0);  rot_pair<1, 9>(s, n0);
    rot_pair<2,10>(s, n0);  rot_pair<3,11>(s, n0);
    rot_pair<4,12>(s, n0);  rot_pair<5,13>(s, n0);
    rot_pair<6,14>(s, n0);  rot_pair<7,15>(s, n0);
    rot_pair<0, 4>(s, n1);  rot_pair<1, 5>(s, n1);
    rot_pair<2, 6>(s, n1);  rot_pair<3, 7>(s, n1);
    rot_pair<0, 2>(s, n2a); rot_pair<1, 3>(s, n2a);
    rot_pair<4, 6>(s, n2b); rot_pair<5, 7>(s, n2b);
    rot_pair<0, 1>(s, n3a); rot_pair<2, 3>(s, n3b);
    rot_pair<4, 5>(s, n3c); rot_pair<6, 7>(s, n3d);
}

// Full gate block of one channel from prefetched register matrices.
__device__ __forceinline__ void gates_from_regs(f2* s, const GateM* g,
                                                bool skip_first) {
    if (!skip_first) apply_gate<8>(s, g[0]);
    apply_gate<4>(s, g[1]);
    apply_gate<2>(s, g[2]);
    apply_gate<1>(s, g[3]);
    apply_cnot<8, 4>(s); apply_cnot<4, 2>(s);
    apply_cnot<2, 1>(s); apply_cnot<1, 8>(s);
    apply_gate<8>(s, g[4]);
    apply_gate<4>(s, g[5]);
    apply_gate<2>(s, g[6]);
    apply_gate<1>(s, g[7]);
    apply_cnot<8, 2>(s); apply_cnot<4, 1>(s);
    apply_cnot<2, 8>(s); apply_cnot<1, 4>(s);
}

__global__ __launch_bounds__(256, 2) void qconv_kernel(
        const float* __restrict__ x,     // (32, 4, 64, 64)
        const float* __restrict__ wts,   // (4, 2, 4, 3)
        float* __restrict__ out) {       // (32, 16, 64, 64)
    __shared__ float smat[32 * 16];      // 2 KB: 32 gates x 4 entries x {re,re,-im,im}
    __shared__ float tile[6 * 4 * 64];   // 6 KB: rows y0-1..y0+4, 4 channels

    const int tid = threadIdx.x;
    const int blk = blockIdx.x;
    const int b  = blk >> 4;             // image
    const int y0 = (blk & 15) << 2;      // first of 4 rows

    // --- build packed Rot matrices (one thread per gate) ---
    if (tid < 32) {
        const float phi   = wts[tid*3 + 0];
        const float theta = wts[tid*3 + 1];
        const float omega = wts[tid*3 + 2];
        float st, ct; __sincosf(0.5f * theta,         &st, &ct);
        float sA, cA; __sincosf(0.5f * (phi + omega), &sA, &cA);
        float sB, cB; __sincosf(0.5f * (phi - omega), &sB, &cB);
        float* g = &smat[tid * 16];
        // entry: {re, re, -im, im}
        g[0]  =  cA*ct; g[1]  =  cA*ct; g[2]  =  sA*ct; g[3]  = -sA*ct; // m00
        g[4]  = -cB*st; g[5]  = -cB*st; g[6]  =  sB*st; g[7]  = -sB*st; // m01
        g[8]  =  cB*st; g[9]  =  cB*st; g[10] =  sB*st; g[11] = -sB*st; // m10
        g[12] =  cA*ct; g[13] =  cA*ct; g[14] = -sA*ct; g[15] =  sA*ct; // m11
    }

    // --- stage input tile (coalesced), pad rows with 0.01 ---
    const float* xb = x + (size_t)b * 16384;
    #pragma unroll
    for (int i = 0; i < 6; ++i) {
        const int e = tid + i * 256;          // [r][ch][col]
        const int r = e >> 8, ch = (e >> 6) & 3, col = e & 63;
        const int gy = y0 - 1 + r;
        float v = 0.01f;
        if ((unsigned)gy < 64u) v = xb[ch * 4096 + gy * 64 + col];
        tile[e] = v;
    }
    __syncthreads();

    const int ly = tid >> 6, xc = tid & 63;

    // --- hoist all 4 channels' squared patches into registers ---
    float q[4][9];
    #pragma unroll
    for (int dy = 0; dy < 3; ++dy) {
        const float* row = tile + (ly + dy) * 256;
        #pragma unroll
        for (int dx = 0; dx < 3; ++dx) {
            const int col = xc - 1 + dx;
            const int colc = min(max(col, 0), 63);
            const bool in = (unsigned)col < 64u;
            #pragma unroll
            for (int ic = 0; ic < 4; ++ic) {
                float v = row[ic * 64 + colc];
                v = in ? v : 0.01f;
                q[ic][dy*3 + dx] = v * v;
            }
        }
    }

    f2 s[16];

    // --- channel 0: prefetch gates, then Mottonen on |0> (real amplitudes) ---
    {
        GateM g[8];
        #pragma unroll
        for (int i = 0; i < 8; ++i) g[i] = load_gate(smat + i * 16);

        const float* Q = q[0];
        const float S = ((Q[0]+Q[1]) + (Q[2]+Q[3])) +
                        ((Q[4]+Q[5]) + (Q[6]+Q[7])) + Q[8];
        const bool ok = S > 1e-30f;
        const float rs = __builtin_amdgcn_rsqf(fmaxf(S, 1e-37f));
        float ar[9];
        #pragma unroll
        for (int j = 0; j < 9; ++j) {
            const float a = __builtin_amdgcn_sqrtf(Q[j]) * rs;
            ar[j] = ok ? a : (j == 0 ? 1.0f : 0.0f);
        }
        // wire-0 gate (stride 8) on a real, 9-sparse state: defines all of s[]
        const f2 m00 = f2{g[0].m00rr.x, g[0].m00ni.y};   // (re, im)
        const f2 m01 = f2{g[0].m01rr.x, g[0].m01ni.y};
        const f2 m10 = f2{g[0].m10rr.x, g[0].m10ni.y};
        const f2 m11 = f2{g[0].m11rr.x, g[0].m11ni.y};
        s[0] = pkfma(f2{ar[8], ar[8]}, m01, f2{ar[0], ar[0]} * m00);
        s[8] = pkfma(f2{ar[8], ar[8]}, m11, f2{ar[0], ar[0]} * m10);
        #pragma unroll
        for (int j = 1; j < 8; ++j) {
            s[j]     = f2{ar[j], ar[j]} * m00;
            s[j + 8] = f2{ar[j], ar[j]} * m10;
        }
        gates_from_regs(s, g, /*skip_first=*/true);
    }

    // --- channels 1..3: prefetch gates, cascade, gates ---
    #pragma unroll
    for (int ic = 1; ic < 4; ++ic) {
        GateM g[8];
        #pragma unroll
        for (int i = 0; i < 8; ++i) g[i] = load_gate(smat + ic * 128 + i * 16);
        cascade(s, q[ic]);
        gates_from_regs(s, g, /*skip_first=*/false);
    }

    // --- probabilities -> clipped output, (b, 16, 64, 64) ---
    float* ob = out + (size_t)b * (16 * 4096) + (y0 + ly) * 64 + xc;
    #pragma unroll
    for (int m = 0; m < 16; ++m) {
        const float p = s[m].x * s[m].x + s[m].y * s[m].y;
        ob[m * 4096] = fminf(p * 8.0f, 1.0f);
    }
}

extern "C" void kernel_launch(void* const* d_in, const int* in_sizes, int n_in,
                              void* d_out, int out_size, void* d_ws, size_t ws_size,
                              hipStream_t stream) {
    const float* x   = (const float*)d_in[0];
    const float* wts = (const float*)d_in[1];
    float* out = (float*)d_out;
    qconv_kernel<<<512, 256, 0, stream>>>(x, wts, out);
}

// Round 5
// 20.092 us; speedup vs baseline: 1.0072x; 1.0072x over previous
//
#include <hip/hip_runtime.h>

// ---------------------------------------------------------------------------
// Quantum conv2d, packed-fp32, ROLLED channel loop (I$-friendly).
// All 4 channels share one loop body (~8KB code): init s=|0>, per channel
// {prefetch 8 gate matrices, read 3x3 patch from LDS tile, Mottonen cascade,
// 8 Rot gates + 2 CNOT rings}. State f2[16] in registers, complex MAC =
// 2x v_pk_fma_f32, gate matrices pre-packed {re,re,-im,im} in LDS.
// ---------------------------------------------------------------------------

typedef float f2 __attribute__((ext_vector_type(2)));

__device__ __forceinline__ f2 pkfma(f2 a, f2 b, f2 c) {
    return __builtin_elementwise_fma(a, b, c);
}
__device__ __forceinline__ f2 swap2(f2 v) {
    return __builtin_shufflevector(v, v, 1, 0);
}

struct GateM { f2 m00rr, m00ni, m01rr, m01ni, m10rr, m10ni, m11rr, m11ni; };

__device__ __forceinline__ GateM load_gate(const float* gp) {
    const float4* p = (const float4*)gp;
    const float4 e0 = p[0], e1 = p[1], e2 = p[2], e3 = p[3];
    GateM G;
    G.m00rr = f2{e0.x, e0.y}; G.m00ni = f2{e0.z, e0.w};
    G.m01rr = f2{e1.x, e1.y}; G.m01ni = f2{e1.z, e1.w};
    G.m10rr = f2{e2.x, e2.y}; G.m10ni = f2{e2.z, e2.w};
    G.m11rr = f2{e3.x, e3.y}; G.m11ni = f2{e3.z, e3.w};
    return G;
}

template<int STRIDE>
__device__ __forceinline__ void apply_gate(f2* s, const GateM G) {
    #pragma unroll
    for (int m0 = 0; m0 < 16; ++m0) {
        if (m0 & STRIDE) continue;
        const int m1 = m0 | STRIDE;
        const f2 a = s[m0], b = s[m1];
        const f2 as = swap2(a), bs = swap2(b);
        f2 o0 = G.m00rr * a;
        o0 = pkfma(G.m00ni, as, o0);
        o0 = pkfma(G.m01rr, b,  o0);
        o0 = pkfma(G.m01ni, bs, o0);
        f2 o1 = G.m10rr * a;
        o1 = pkfma(G.m10ni, as, o1);
        o1 = pkfma(G.m11rr, b,  o1);
        o1 = pkfma(G.m11ni, bs, o1);
        s[m0] = o0; s[m1] = o1;
    }
}

template<int BC, int BT>
__device__ __forceinline__ void apply_cnot(f2* s) {
    #pragma unroll
    for (int m = 0; m < 16; ++m) {
        if ((m & BC) && !(m & BT)) {
            const int m2 = m | BT;
            const f2 t = s[m]; s[m] = s[m2]; s[m2] = t;
        }
    }
}

struct Node { f2 cc, ss, ns; };

// Multiplexed-RY node from un-normalized child sums (scale cancels).
__device__ __forceinline__ Node node_cs(float lo, float hi) {
    const float den = lo + hi;
    const bool ok = den > 1e-30f;
    const float rs = __builtin_amdgcn_rsqf(fmaxf(den, 1e-37f));
    const float c = ok ? __builtin_amdgcn_sqrtf(lo) * rs : 1.0f;
    const float s = ok ? __builtin_amdgcn_sqrtf(hi) * rs : 0.0f;
    return Node{f2{c, c}, f2{s, s}, f2{-s, -s}};
}

template<int I0, int I1>
__device__ __forceinline__ void rot_pair(f2* s, const Node& n) {
    const f2 a = s[I0], b = s[I1];
    s[I0] = pkfma(n.cc, a, n.ns * b);
    s[I1] = pkfma(n.ss, a, n.cc * b);
}

__device__ __forceinline__ void cascade(f2* s, const float* Q) {
    const float s01 = Q[0]+Q[1], s23 = Q[2]+Q[3];
    const float s45 = Q[4]+Q[5], s67 = Q[6]+Q[7];
    const float s03 = s01+s23, s47 = s45+s67, s07 = s03+s47;
    const Node n0  = node_cs(s07,  Q[8]);   // t=0
    const Node n1  = node_cs(s03,  s47);    // t=1 b=0 (b=1 identity)
    const Node n2a = node_cs(s01,  s23);    // t=2 b=0
    const Node n2b = node_cs(s45,  s67);    // t=2 b=1 (b=2,3 identity)
    const Node n3a = node_cs(Q[0], Q[1]);   // t=3 b=0
    const Node n3b = node_cs(Q[2], Q[3]);   // t=3 b=1
    const Node n3c = node_cs(Q[4], Q[5]);   // t=3 b=2
    const Node n3d = node_cs(Q[6], Q[7]);   // t=3 b=3 (b=4..7 identity)

    rot_pair<0, 8>(s, n0);  rot_pair<1, 9>(s, n0);
    rot_pair<2,10>(s, n0);  rot_pair<3,11>(s, n0);
    rot_pair<4,12>(s, n0);  rot_pair<5,13>(s, n0);
    rot_pair<6,14>(s, n0);  rot_pair<7,15>(s, n0);
    rot_pair<0, 4>(s, n1);  rot_pair<1, 5>(s, n1);
    rot_pair<2, 6>(s, n1);  rot_pair<3, 7>(s, n1);
    rot_pair<0, 2>(s, n2a); rot_pair<1, 3>(s, n2a);
    rot_pair<4, 6>(s, n2b); rot_pair<5, 7>(s, n2b);
    rot_pair<0, 1>(s, n3a); rot_pair<2, 3>(s, n3b);
    rot_pair<4, 5>(s, n3c); rot_pair<6, 7>(s, n3d);
}

__global__ __launch_bounds__(256, 2) void qconv_kernel(
        const float* __restrict__ x,     // (32, 4, 64, 64)
        const float* __restrict__ wts,   // (4, 2, 4, 3)
        float* __restrict__ out) {       // (32, 16, 64, 64)
    __shared__ float smat[32 * 16];      // 2 KB: 32 gates x 4 entries x {re,re,-im,im}
    __shared__ float tile[6 * 4 * 64];   // 6 KB: rows y0-1..y0+4, 4 channels

    const int tid = threadIdx.x;
    const int blk = blockIdx.x;
    const int b  = blk >> 4;             // image
    const int y0 = (blk & 15) << 2;      // first of 4 rows

    // --- build packed Rot matrices (one thread per gate) ---
    if (tid < 32) {
        const float phi   = wts[tid*3 + 0];
        const float theta = wts[tid*3 + 1];
        const float omega = wts[tid*3 + 2];
        float st, ct; __sincosf(0.5f * theta,         &st, &ct);
        float sA, cA; __sincosf(0.5f * (phi + omega), &sA, &cA);
        float sB, cB; __sincosf(0.5f * (phi - omega), &sB, &cB);
        float* g = &smat[tid * 16];
        // entry: {re, re, -im, im}
        g[0]  =  cA*ct; g[1]  =  cA*ct; g[2]  =  sA*ct; g[3]  = -sA*ct; // m00
        g[4]  = -cB*st; g[5]  = -cB*st; g[6]  =  sB*st; g[7]  = -sB*st; // m01
        g[8]  =  cB*st; g[9]  =  cB*st; g[10] =  sB*st; g[11] = -sB*st; // m10
        g[12] =  cA*ct; g[13] =  cA*ct; g[14] = -sA*ct; g[15] =  sA*ct; // m11
    }

    // --- stage input tile (coalesced), pad rows with 0.01 ---
    const float* xb = x + (size_t)b * 16384;
    #pragma unroll
    for (int i = 0; i < 6; ++i) {
        const int e = tid + i * 256;          // [r][ch][col]
        const int r = e >> 8, ch = (e >> 6) & 3, col = e & 63;
        const int gy = y0 - 1 + r;
        float v = 0.01f;
        if ((unsigned)gy < 64u) v = xb[ch * 4096 + gy * 64 + col];
        tile[e] = v;
    }
    __syncthreads();

    const int ly = tid >> 6, xc = tid & 63;
    const int colm = min(max(xc - 1, 0), 63);   // clamped col for dx=0
    const int colp = min(xc + 1, 63);           // clamped col for dx=2
    const bool inm = xc > 0, inp = xc < 63;

    f2 s[16];
    #pragma unroll
    for (int i = 0; i < 16; ++i) s[i] = f2{0.0f, 0.0f};
    s[0] = f2{1.0f, 0.0f};

    // --- 4 channels, ROLLED loop (small code -> I$ resident) ---
    #pragma unroll 1
    for (int ic = 0; ic < 4; ++ic) {
        // prefetch this channel's 8 gate matrices (issue early)
        GateM g[8];
        const float* cb = smat + ic * 128;
        #pragma unroll
        for (int i = 0; i < 8; ++i) g[i] = load_gate(cb + i * 16);

        // squared 3x3 patch from LDS tile [6][4][64]
        float q[9];
        #pragma unroll
        for (int dy = 0; dy < 3; ++dy) {
            const float* row = tile + ((ly + dy) * 4 + ic) * 64;
            float vm = row[colm]; vm = inm ? vm : 0.01f;
            float v0 = row[xc];
            float vp = row[colp]; vp = inp ? vp : 0.01f;
            q[dy*3 + 0] = vm * vm;
            q[dy*3 + 1] = v0 * v0;
            q[dy*3 + 2] = vp * vp;
        }

        cascade(s, q);

        apply_gate<8>(s, g[0]);
        apply_gate<4>(s, g[1]);
        apply_gate<2>(s, g[2]);
        apply_gate<1>(s, g[3]);
        apply_cnot<8, 4>(s); apply_cnot<4, 2>(s);
        apply_cnot<2, 1>(s); apply_cnot<1, 8>(s);
        apply_gate<8>(s, g[4]);
        apply_gate<4>(s, g[5]);
        apply_gate<2>(s, g[6]);
        apply_gate<1>(s, g[7]);
        apply_cnot<8, 2>(s); apply_cnot<4, 1>(s);
        apply_cnot<2, 8>(s); apply_cnot<1, 4>(s);
    }

    // --- probabilities -> clipped output, (b, 16, 64, 64) ---
    float* ob = out + (size_t)b * (16 * 4096) + (y0 + ly) * 64 + xc;
    #pragma unroll
    for (int m = 0; m < 16; ++m) {
        const float p = s[m].x * s[m].x + s[m].y * s[m].y;
        ob[m * 4096] = fminf(p * 8.0f, 1.0f);
    }
}

extern "C" void kernel_launch(void* const* d_in, const int* in_sizes, int n_in,
                              void* d_out, int out_size, void* d_ws, size_t ws_size,
                              hipStream_t stream) {
    const float* x   = (const float*)d_in[0];
    const float* wts = (const float*)d_in[1];
    float* out = (float*)d_out;
    qconv_kernel<<<512, 256, 0, stream>>>(x, wts, out);
}